// Round 4
// baseline (651.520 us; speedup 1.0000x reference)
//
#include <hip/hip_runtime.h>

// Shapes (fixed by reference):
//   x : (32, 256, 64, 64) fp32   -> BS=32, C=256, HW=4096
//   w1: (32, 256)   b1: (32,)    -> HID=32
//   w2: (2, 512, 32) b2: (2,512) -> K=2, 2C=512
// out: (32, 256, 64, 64) fp32
//
// Two dispatches (cooperative launch does NOT work in this harness — R2
// failed with the empty-stub error signature, i.e. kernel never ran):
//   A) pool each (b,c) row; last-arriving block per batch (threadfence +
//      atomic counter, rocPRIM-lookback pattern) computes the MLP coeffs.
//   B) apply out = max(x*a0+b0, x*a1+b1); x re-read is L3-warm from A.

#define BS   32
#define CCH  256
#define HW   4096
#define HID  32

// native clang vector type — __builtin_nontemporal_store rejects HIP's
// float4 class (R3 compile error), but accepts ext_vector_type.
typedef float vfloat4 __attribute__((ext_vector_type(4)));

// ---------------- Kernel A: pool + (last block per batch) coefficients ----
__global__ __launch_bounds__(256) void pool_coef_kernel(
    const float* __restrict__ x,
    const float* __restrict__ w1,
    const float* __restrict__ b1,
    const float* __restrict__ w2,
    const float* __restrict__ b2,
    int*   __restrict__ cnt,      // [BS], zeroed before launch
    float* __restrict__ pooled,   // [BS*CCH]
    float* __restrict__ A,        // [BS*2*CCH]
    float* __restrict__ Bc)       // [BS*2*CCH]
{
    const int bc   = blockIdx.x;          // 0..8191, one (b,c) row per block
    const int b    = bc >> 8;
    const int t    = threadIdx.x;
    const int lane = t & 63, wave = t >> 6;

    // ---- pool this row: 4096 floats, 4x float4 per thread ----
    const float4* xp = (const float4*)(x + (size_t)bc * HW);
    float s = 0.f;
#pragma unroll
    for (int i = 0; i < 4; ++i) {
        float4 v = xp[t + i * 256];
        s += (v.x + v.y) + (v.z + v.w);
    }
#pragma unroll
    for (int off = 32; off > 0; off >>= 1)
        s += __shfl_down(s, off, 64);

    __shared__ float wsum[4];
    __shared__ int   isLast;
    if (lane == 0) wsum[wave] = s;
    __syncthreads();
    if (t == 0) {
        pooled[bc] = (wsum[0] + wsum[1] + wsum[2] + wsum[3]) * (1.f / HW);
        __threadfence();                       // release: pooled[bc] visible
        int old = atomicAdd(&cnt[b], 1);       // device-scope by default
        isLast = (old == CCH - 1);
    }
    __syncthreads();
    if (!isLast) return;

    // ---- last block of batch b: compute all coefficients for b ----
    __threadfence();                           // acquire
    __shared__ float pl[CCH];
    __shared__ float hpart[256];
    __shared__ float hval[HID];
    pl[t] = ((volatile const float*)pooled)[b * CCH + t];
    __syncthreads();
    {   // h partials: thread t -> hid=t/8, chunk=t%8 (32 MACs each)
        const int hid = t >> 3, part = t & 7;
        float s2 = 0.f;
        const float* w1p = w1 + hid * CCH + part * 32;
        const float* plp = pl + part * 32;
#pragma unroll
        for (int j = 0; j < 32; ++j) s2 += plp[j] * w1p[j];
        hpart[t] = s2;
    }
    __syncthreads();
    if (t < HID) {
        float s2 = b1[t];
#pragma unroll
        for (int p = 0; p < 8; ++p) s2 += hpart[t * 8 + p];
        hval[t] = s2 > 0.f ? s2 : 0.f;         // relu
    }
    __syncthreads();
    // 1024 (k,o) sigmoid outputs, 256 threads -> 4 each
    for (int idx = t; idx < 2 * 2 * CCH; idx += 256) {
        const int k = idx >> 9;                // / 512
        const int o = idx & 511;               // % 512
        float s2 = b2[k * 512 + o];
        const float* w2p = w2 + (size_t)(k * 512 + o) * HID;
#pragma unroll
        for (int j = 0; j < HID; ++j) s2 += w2p[j] * hval[j];
        const float d = 2.f / (1.f + __expf(-s2)) - 1.f;   // 2*sigmoid-1
        const int c = o >> 1;
        const float initv = (k == 0) ? 1.f : 0.f;          // init vecs = [1,0]
        if ((o & 1) == 0) A [(b * 2 + k) * CCH + c] = initv + d;        // LA=1.0
        else              Bc[(b * 2 + k) * CCH + c] = initv + 0.5f * d; // LB=0.5
    }
}

// ---------------- Kernel B: apply + max over K ----------------------------
// One float4 per thread; a full wave64 (256 floats) stays inside one (b,c)
// row so the four coefficient loads are wave-uniform (L1 broadcast).
// Nontemporal stores: out is never re-read, keep x resident in L2/L3.
__global__ __launch_bounds__(256) void apply_kernel(const float* __restrict__ x,
                                                    const float* __restrict__ A,
                                                    const float* __restrict__ Bc,
                                                    float* __restrict__ out) {
    const size_t i4 = (size_t)blockIdx.x * 256 + threadIdx.x;
    const int bc = (int)(i4 >> 10);       // 1024 float4 per (b,c)
    const int b = bc >> 8;
    const int c = bc & 255;
    const float a0 = A [(b * 2 + 0) * CCH + c];
    const float a1 = A [(b * 2 + 1) * CCH + c];
    const float b0 = Bc[(b * 2 + 0) * CCH + c];
    const float b1 = Bc[(b * 2 + 1) * CCH + c];
    const float4 v = ((const float4*)x)[i4];
    vfloat4 r;
    r.x = fmaxf(v.x * a0 + b0, v.x * a1 + b1);
    r.y = fmaxf(v.y * a0 + b0, v.y * a1 + b1);
    r.z = fmaxf(v.z * a0 + b0, v.z * a1 + b1);
    r.w = fmaxf(v.w * a0 + b0, v.w * a1 + b1);
    __builtin_nontemporal_store(r, (vfloat4*)out + i4);
}

extern "C" void kernel_launch(void* const* d_in, const int* in_sizes, int n_in,
                              void* d_out, int out_size, void* d_ws, size_t ws_size,
                              hipStream_t stream) {
    const float* x  = (const float*)d_in[0];
    const float* w1 = (const float*)d_in[1];
    const float* b1 = (const float*)d_in[2];
    const float* w2 = (const float*)d_in[3];
    const float* b2 = (const float*)d_in[4];
    float* out = (float*)d_out;

    // ws layout: cnt[32] int | pooled[8192] | A[2048] | B[2048] (floats)
    int*   cnt    = (int*)d_ws;
    float* pooled = (float*)d_ws + 32;
    float* A      = pooled + BS * CCH;
    float* Bc     = A + BS * 2 * CCH;

    (void)hipMemsetAsync(cnt, 0, BS * sizeof(int), stream); // ws poisoned 0xAA
    pool_coef_kernel<<<BS * CCH, 256, 0, stream>>>(x, w1, b1, w2, b2,
                                                   cnt, pooled, A, Bc);
    const int n4 = (BS * CCH * HW) / 4;                // 8,388,608 float4
    apply_kernel<<<n4 / 256, 256, 0, stream>>>(x, A, Bc, out);
}